// Round 6
// baseline (322.361 us; speedup 1.0000x reference)
//
#include <hip/hip_runtime.h>
#include <hip/hip_bf16.h>

#define H 2048
#define NH 32
#define HD 64
#define BB 2
#define SS 2048
#define MM (BB*SS)   // 4096 rows

typedef __attribute__((ext_vector_type(8))) short bf16x8;
typedef __attribute__((ext_vector_type(4))) float f32x4;
typedef __attribute__((ext_vector_type(16))) float f32x16;
typedef unsigned short u16;
typedef unsigned int u32;
typedef __attribute__((ext_vector_type(4))) u32 u32x4;

static __device__ __forceinline__ u16 f2bf(float f){
  union { float f; u32 i; } v; v.f = f;
  u32 x = v.i;
  return (u16)((x + 0x7FFFu + ((x >> 16) & 1u)) >> 16);  // RNE
}
static __device__ __forceinline__ float bf2f(u16 u){
  union { u32 i; float f; } v; v.i = ((u32)u) << 16; return v.f;
}
// packed f32x2 -> bf16x2 (low = a, high = b), single HW instr
static __device__ __forceinline__ u32 pk2(float a, float b){
  u32 r;
  asm("v_cvt_pk_bf16_f32 %0, %1, %2" : "=v"(r) : "v"(a), "v"(b));
  return r;
}

static __device__ __forceinline__ void gload16(const u16* g, u16* l){
  __builtin_amdgcn_global_load_lds((const __attribute__((address_space(1))) void*)g,
                                   (__attribute__((address_space(3))) void*)l, 16, 0, 0);
}

// ---------------- 1. X f32 -> bf16 ----------------
__global__ void k_cvt(const float* __restrict__ src, u16* __restrict__ dst){
  const int i = (blockIdx.x * 256 + threadIdx.x) * 4;
  float4 v = *(const float4*)(src + i);
  ushort4 o;
  o.x = f2bf(v.x); o.y = f2bf(v.y); o.z = f2bf(v.z); o.w = f2bf(v.w);
  *(ushort4*)(dst + i) = o;
}

// ---------------- 2. W [K][N] f32 -> Wt [N][K] bf16 ----------------
__global__ void k_wtrans(const float* __restrict__ w0, const float* __restrict__ w1,
                         const float* __restrict__ w2, const float* __restrict__ w3,
                         u16* __restrict__ d0, u16* __restrict__ d1,
                         u16* __restrict__ d2, u16* __restrict__ d3){
  __shared__ float tile[32][33];
  const int z = blockIdx.z;
  const float* w = z==0 ? w0 : z==1 ? w1 : z==2 ? w2 : w3;
  u16* d        = z==0 ? d0 : z==1 ? d1 : z==2 ? d2 : d3;
  const int n0 = blockIdx.x * 32, k0 = blockIdx.y * 32;
  const int tx = threadIdx.x, ty = threadIdx.y;  // 32 x 8
  #pragma unroll
  for (int j = 0; j < 4; j++)
    tile[ty + 8*j][tx] = w[(size_t)(k0 + ty + 8*j) * H + n0 + tx];
  __syncthreads();
  #pragma unroll
  for (int j = 0; j < 4; j++)
    d[(size_t)(n0 + ty + 8*j) * H + k0 + tx] = f2bf(tile[tx][ty + 8*j]);
}

// ---------------- 3. QKV GEMM: 256x256 tile, 8-phase, counted vmcnt ----------------
// C[M][N] = A[M][K] * Bt[N][K]^T, bf16 out. 512 thr = 8 waves (2M x 4N),
// per-wave 128x64 output (acc[8][4]). BK=64, 2 LDS slots (128 KiB total).
// Per K-tile: 4 phases {ds_read frags; setprio(1); 16 MFMA; setprio(0); s_barrier},
// then stage(kt+2) into freed slot + s_waitcnt vmcnt(8) (never drains to 0) + barrier.
// LDS swizzle col ^= (row&7)*8 on both sides (pre-swizzled global src for gload_lds).
__global__ __launch_bounds__(512, 2) void k_gemm8(
    const u16* __restrict__ A,
    const u16* __restrict__ B0, const u16* __restrict__ B1, const u16* __restrict__ B2,
    u16* __restrict__ C0, u16* __restrict__ C1, u16* __restrict__ C2,
    int M, int N, int K){
  __shared__ __align__(16) u16 As[2][256][64];
  __shared__ __align__(16) u16 Bs[2][256][64];
  const int z = blockIdx.y;
  const u16* Bt = z==0 ? B0 : z==1 ? B1 : B2;
  u16* C        = z==0 ? C0 : z==1 ? C1 : C2;
  // bijective XCD swizzle over the 128 xy-blocks (128 % 8 == 0)
  const int flat = blockIdx.x;
  const int id = (flat & 7) * 16 + (flat >> 3);
  const int gx = id & 15, gy = id >> 4;
  const int m0 = gx * 256, n0 = gy * 256;
  const int t = threadIdx.x, w = t >> 6, l = t & 63;
  const int wm = w >> 2, wn = w & 3;           // wave tile: rows wm*128, cols wn*64
  const int lrow = l & 15, lk = (l >> 4) * 8;
  const int sw = (lrow & 7) * 8;               // read-side swizzle
  const int sr = t >> 3, sc = (t & 7) * 8;     // staging: 64 rows x 8 chunks per pass
  const int ssc = sc ^ ((sr & 7) * 8);         // pre-swizzled global col
  const int NK = K >> 6;

  auto stage = [&](int kt, int u){
    const int kb = kt * 64 + ssc;
    #pragma unroll
    for (int c = 0; c < 4; c++)
      gload16(A + (size_t)(m0 + c*64 + sr) * K + kb, &As[u][c*64 + sr][sc]);
    #pragma unroll
    for (int c = 0; c < 4; c++)
      gload16(Bt + (size_t)(n0 + c*64 + sr) * K + kb, &Bs[u][c*64 + sr][sc]);
  };

  f32x4 acc[8][4] = {};

  // prologue: stage K-tiles 0 and 1; wait tile 0 (tile 1 stays in flight)
  stage(0, 0);
  stage(1, 1);
  asm volatile("s_waitcnt vmcnt(8)" ::: "memory");
  __builtin_amdgcn_s_barrier();

#define APHASE(MB)                                                              \
  {                                                                             \
    bf16x8 afr0 = *(const bf16x8*)&As[u][wm*128 + (MB)*16   + lrow][lk ^ sw];   \
    bf16x8 afr1 = *(const bf16x8*)&As[u][wm*128 + (MB)*16   + lrow][(32+lk) ^ sw]; \
    bf16x8 afr2 = *(const bf16x8*)&As[u][wm*128 + (MB+1)*16 + lrow][lk ^ sw];   \
    bf16x8 afr3 = *(const bf16x8*)&As[u][wm*128 + (MB+1)*16 + lrow][(32+lk) ^ sw]; \
    __builtin_amdgcn_s_setprio(1);                                              \
    _Pragma("unroll")                                                           \
    for (int n = 0; n < 4; n++){                                                \
      acc[MB][n]   = __builtin_amdgcn_mfma_f32_16x16x32_bf16(afr0, bfr[n][0], acc[MB][n],   0,0,0); \
      acc[MB][n]   = __builtin_amdgcn_mfma_f32_16x16x32_bf16(afr1, bfr[n][1], acc[MB][n],   0,0,0); \
      acc[MB+1][n] = __builtin_amdgcn_mfma_f32_16x16x32_bf16(afr2, bfr[n][0], acc[MB+1][n], 0,0,0); \
      acc[MB+1][n] = __builtin_amdgcn_mfma_f32_16x16x32_bf16(afr3, bfr[n][1], acc[MB+1][n], 0,0,0); \
    }                                                                           \
    __builtin_amdgcn_s_setprio(0);                                              \
    __builtin_amdgcn_s_barrier();                                               \
  }

  #pragma unroll 1
  for (int kt = 0; kt < NK; ++kt){
    const int u = kt & 1;
    bf16x8 bfr[4][2];
    // phase 0 also loads the wave's 8 shared B fragments
    #pragma unroll
    for (int n = 0; n < 4; n++){
      const int row = wn*64 + n*16 + lrow;
      bfr[n][0] = *(const bf16x8*)&Bs[u][row][lk ^ sw];
      bfr[n][1] = *(const bf16x8*)&Bs[u][row][(32 + lk) ^ sw];
    }
    APHASE(0)
    APHASE(2)
    APHASE(4)
    APHASE(6)
    // all waves finished reading slot u (phase barrier above) -> safe to overwrite
    if (kt + 2 < NK){
      stage(kt + 2, u);
      asm volatile("s_waitcnt vmcnt(8)" ::: "memory");   // tile kt+1 landed
    } else if (kt + 1 < NK){
      asm volatile("s_waitcnt vmcnt(0)" ::: "memory");   // final tile landed
    }
    __builtin_amdgcn_s_barrier();
  }
#undef APHASE

  #pragma unroll
  for (int m = 0; m < 8; m++)
    #pragma unroll
    for (int n = 0; n < 4; n++)
      #pragma unroll
      for (int r = 0; r < 4; r++){
        const int row = m0 + wm*128 + m*16 + (l >> 4)*4 + r;
        const int col = n0 + wn*64 + n*16 + lrow;
        C[(size_t)row * N + col] = f2bf(acc[m][n][r]);
      }
}

// ---------------- 3b/6. GEMM C[M][N] = A[M][K] * Bt[N][K]^T (128^2, out-proj) ----------------
template<typename OutT>
__global__ __launch_bounds__(256, 2) void k_gemm(
    const u16* __restrict__ A,
    const u16* __restrict__ B0, const u16* __restrict__ B1, const u16* __restrict__ B2,
    OutT* __restrict__ C0, OutT* __restrict__ C1, OutT* __restrict__ C2,
    int M, int N, int K){
  __shared__ __align__(16) u16 As[128][64];
  __shared__ __align__(16) u16 Bs[128][64];
  const int z = blockIdx.z;
  const u16* Bt = z==0 ? B0 : z==1 ? B1 : B2;
  OutT* C       = z==0 ? C0 : z==1 ? C1 : C2;
  const int t = threadIdx.x;
  const int w = t >> 6, l = t & 63;
  const int m0 = blockIdx.x * 128, n0 = blockIdx.y * 128;
  const int srow = t >> 3, scol = (t & 7) * 8;      // staging: 32 rows x 8 chunks
  const int lrow = l & 15, lk = (l >> 4) * 8;       // fragment lane mapping
  const int wr = (w >> 1) * 64, wc = (w & 1) * 64;  // wave tile
  f32x4 acc[4][4] = {};
  for (int k0 = 0; k0 < K; k0 += 64){
    __syncthreads();
    #pragma unroll
    for (int c = 0; c < 4; c++)
      gload16(A + (size_t)(m0 + c*32 + srow) * K + k0 + scol, &As[c*32 + srow][scol]);
    #pragma unroll
    for (int c = 0; c < 4; c++)
      gload16(Bt + (size_t)(n0 + c*32 + srow) * K + k0 + scol, &Bs[c*32 + srow][scol]);
    __syncthreads();
    #pragma unroll
    for (int kk = 0; kk < 2; kk++){
      bf16x8 a[4], b[4];
      #pragma unroll
      for (int m = 0; m < 4; m++) a[m] = *(const bf16x8*)&As[wr + m*16 + lrow][kk*32 + lk];
      #pragma unroll
      for (int n = 0; n < 4; n++) b[n] = *(const bf16x8*)&Bs[wc + n*16 + lrow][kk*32 + lk];
      #pragma unroll
      for (int m = 0; m < 4; m++)
        #pragma unroll
        for (int n = 0; n < 4; n++)
          acc[m][n] = __builtin_amdgcn_mfma_f32_16x16x32_bf16(a[m], b[n], acc[m][n], 0, 0, 0);
    }
  }
  #pragma unroll
  for (int m = 0; m < 4; m++)
    #pragma unroll
    for (int n = 0; n < 4; n++)
      #pragma unroll
      for (int r = 0; r < 4; r++){
        const int row = m0 + wr + m*16 + (l >> 4)*4 + r;
        const int col = n0 + wc + n*16 + lrow;
        const float v = acc[m][n][r];
        if constexpr (sizeof(OutT) == 2) C[(size_t)row * N + col] = (OutT)f2bf(v);
        else                             C[(size_t)row * N + col] = v;
      }
}

// ---------------- 4. RoPE on Q and K, in place ----------------
// Q additionally scaled by log2(e)/sqrt(HD) so attention can use exp2 directly.
__global__ void k_rope(u16* __restrict__ Q, u16* __restrict__ Kp){
  const int idx = blockIdx.x * 256 + threadIdx.x;  // 4096*32*4 threads
  const int quad = idx & 3;
  const int h = (idx >> 2) & 31;
  const int row = idx >> 7;
  const int s = row & (SS - 1);
  const int i0 = quad * 8;
  u16* q = Q  + (size_t)row * H + h * HD;
  u16* k = Kp + (size_t)row * H + h * HD;
  uint4 q1v = *(const uint4*)(q + i0);
  uint4 q2v = *(const uint4*)(q + i0 + 32);
  uint4 k1v = *(const uint4*)(k + i0);
  uint4 k2v = *(const uint4*)(k + i0 + 32);
  u16* q1 = (u16*)&q1v; u16* q2 = (u16*)&q2v;
  u16* k1 = (u16*)&k1v; u16* k2 = (u16*)&k2v;
  const float sf = (float)s;
  const float QSC = 0.18033688011112042f;  // (1/8) * log2(e)
  #pragma unroll
  for (int e = 0; e < 8; e++){
    const int i = i0 + e;
    const float inv = exp2f(-0.4152410118609203f * (float)i);  // 10000^(-i/32)
    float rev = sf * inv * 0.15915494309189535f;               // radians -> revolutions
    rev -= floorf(rev);
    const float sn = __builtin_amdgcn_sinf(rev);
    const float cs = __builtin_amdgcn_cosf(rev);
    const float qa = bf2f(q1[e]), qb = bf2f(q2[e]);
    q1[e] = f2bf((qa*cs - qb*sn) * QSC);
    q2[e] = f2bf((qb*cs + qa*sn) * QSC);
    const float ka = bf2f(k1[e]), kb = bf2f(k2[e]);
    k1[e] = f2bf(ka*cs - kb*sn);
    k2[e] = f2bf(kb*cs + ka*sn);
  }
  *(uint4*)(q + i0)      = q1v;
  *(uint4*)(q + i0 + 32) = q2v;
  *(uint4*)(k + i0)      = k1v;
  *(uint4*)(k + i0 + 32) = k2v;
}

// ---------------- 5. causal flash attention (swapped QK^T, 32x32 mfma) ----------------
// block = 256 thr (4 waves x 32 q-rows = 128 q/block). Block x handles q-tiles
// {15-x, x} -> uniform 36 KV-iterations. Counted-vmcnt pipeline (T4): stage
// tile t+2 each iter; s_waitcnt vmcnt(4) + raw s_barrier (NO vmcnt(0) drain).
// K: 3 LDS buffers via global_load_lds; V: 2-deep reg prefetch -> transposed LDS.
__global__ __launch_bounds__(256, 2) void k_attn(
    const u16* __restrict__ Q, const u16* __restrict__ K,
    const u16* __restrict__ V, u16* __restrict__ O){
  __shared__ __align__(16) u16 Ks[3][64][64];   // swizzled: col ^ (row&7)*8
  __shared__ __align__(16) u16 Vs[2][64][72];   // transposed Vs[d][j], j ^ (d>>3)*8
  const int t = threadIdx.x, w = t >> 6, l = t & 63;
  const int x = blockIdx.x, bh = blockIdx.y;
  const int b = bh >> 5, h = bh & 31;
  const u16* kp = K + (size_t)(b*SS) * H + h * HD;
  const u16* vp = V + (size_t)(b*SS) * H + h * HD;
  const int sr = t >> 3, sc = (t & 7) * 8;      // staging: linear-LDS pattern
  const int ssc = sc ^ ((sr & 7) * 8);          // pre-swizzled global col for K
  const int hi = l >> 5, lq = l & 31;

  auto stageK = [&](int tile, int buf){
    const int jb = tile * 64;
    gload16(kp + (size_t)(jb + sr) * H + ssc,      &Ks[buf][sr][sc]);
    gload16(kp + (size_t)(jb + 32 + sr) * H + ssc, &Ks[buf][32 + sr][sc]);
  };
  auto loadV = [&](int tile, uint4* vv){
    const int jb = tile * 64;
    vv[0] = *(const uint4*)(vp + (size_t)(jb + sr) * H + sc);
    vv[1] = *(const uint4*)(vp + (size_t)(jb + 32 + sr) * H + sc);
  };
  auto publishV = [&](const uint4* vv, int buf){
    #pragma unroll
    for (int c = 0; c < 2; c++){
      const int j = c*32 + sr;
      const u16* pv = (const u16*)&vv[c];
      #pragma unroll
      for (int e = 0; e < 8; e++){
        const int d = sc + e;
        Vs[buf][d][j ^ ((d >> 3) * 8)] = pv[e];
      }
    }
  };

  #pragma unroll 1
  for (int pp = 0; pp < 2; pp++){
    const int qt = pp ? x : (15 - x);           // heavy pass first
    const int NT = 2*qt + 2;                    // even
    const int qw0 = qt*128 + w*32;
    const int qrow = qw0 + lq;                  // this lane's q index

    // Q fragments (B-operand of swapped QK^T): lane holds Q[qrow][c*16 + hi*8 + e]
    const u16* qptr = Q + (size_t)(b*SS + qrow) * H + h * HD + hi*8;
    bf16x8 qf[4];
    #pragma unroll
    for (int c = 0; c < 4; c++) qf[c] = *(const bf16x8*)(qptr + c*16);

    float mrun = -1e30f, lrun = 0.f;
    f32x16 oacc[2] = {};
    uint4 vvE[2], vvO[2];

    // ---- prologue: stage tiles 0 (->vvE) and 1 (->vvO) ----
    stageK(0, 0); loadV(0, vvE);
    stageK(1, 1); loadV(1, vvO);
    asm volatile("s_waitcnt vmcnt(4)" ::: "memory");   // stage(0) complete
    publishV(vvE, 0);
    asm volatile("s_waitcnt lgkmcnt(0)" ::: "memory");
    __builtin_amdgcn_s_barrier();

    // one pipelined body; p = jt&1 (compile-time at call site)
    auto body = [&](int jt, int p, uint4* vvSelf, const uint4* vvOther){
      const int j0 = jt * 64;
      if (jt + 2 < NT){ stageK(jt + 2, (jt + 2) % 3); loadV(jt + 2, vvSelf); }

      if (j0 <= qw0){   // wave has live rows in this tile
        const int kbuf = jt % 3;
        // ---- S^T = K . Q^T ----
        f32x16 sv[2] = {};
        __builtin_amdgcn_s_setprio(1);
        #pragma unroll
        for (int kb = 0; kb < 2; kb++){
          const int row = kb*32 + lq;
          #pragma unroll
          for (int c = 0; c < 4; c++){
            bf16x8 kf = *(const bf16x8*)&Ks[kbuf][row][(c*16 + hi*8) ^ ((row & 7) * 8)];
            sv[kb] = __builtin_amdgcn_mfma_f32_32x32x16_bf16(kf, qf[c], sv[kb], 0, 0, 0);
          }
        }
        __builtin_amdgcn_s_setprio(0);
        // ---- causal mask (diagonal-touching tiles only) ----
        if (j0 + 63 > qw0){
          #pragma unroll
          for (int kb = 0; kb < 2; kb++)
            #pragma unroll
            for (int r = 0; r < 16; r++){
              const int kg = j0 + kb*32 + (r & 3) + 8*(r >> 2) + 4*hi;
              if (kg > qrow) sv[kb][r] = -1e30f;
            }
        }
        // ---- online softmax (exp2 domain), tree reduce, partner lane l^32 ----
        float t16[16], t8[8], t4[4];
        #pragma unroll
        for (int r = 0; r < 16; r++) t16[r] = fmaxf(sv[0][r], sv[1][r]);
        #pragma unroll
        for (int r = 0; r < 8; r++) t8[r] = fmaxf(t16[r], t16[r+8]);
        #pragma unroll
        for (int r = 0; r < 4; r++) t4[r] = fmaxf(t8[r], t8[r+4]);
        float tm = fmaxf(fmaxf(t4[0], t4[2]), fmaxf(t4[1], t4[3]));
        tm = fmaxf(tm, __shfl_xor(tm, 32, 64));
        if (__any(tm > mrun)){       // exact: skipped iff fac == 1.0 for all lanes
          const float mn = fmaxf(mrun, tm);
          const float fac = exp2f(mrun - mn);
          mrun = mn;
          lrun *= fac;
          #pragma unroll
          for (int db = 0; db < 2; db++)
            #pragma unroll
            for (int r = 0; r < 16; r++) oacc[db][r] *= fac;
        }
        #pragma unroll
        for (int kb = 0; kb < 2; kb++)
          #pragma unroll
          for (int r = 0; r < 16; r++) sv[kb][r] = exp2f(sv[kb][r] - mrun);
        float s16[16], s8[8], s4[4];
        #pragma unroll
        for (int r = 0; r < 16; r++) s16[r] = sv[0][r] + sv[1][r];
        #pragma unroll
        for (int r = 0; r < 8; r++) s8[r] = s16[r] + s16[r+8];
        #pragma unroll
        for (int r = 0; r < 4; r++) s4[r] = s8[r] + s8[r+4];
        float rs = (s4[0] + s4[1]) + (s4[2] + s4[3]);
        rs += __shfl_xor(rs, 32, 64);
        lrun += rs;
        // ---- build PV B-frags: cvt_pk pairs, exchange halves via xor-32 ----
        u32x4 pw[4];
        #pragma unroll
        for (int kb = 0; kb < 2; kb++){
          #pragma unroll
          for (int half = 0; half < 2; half++){
            const int rb = half * 8;
            const u32 own0 = pk2(sv[kb][rb+0], sv[kb][rb+1]);
            const u32 own1 = pk2(sv[kb][rb+2], sv[kb][rb+3]);
            const u32 own2 = pk2(sv[kb][rb+4], sv[kb][rb+5]);
            const u32 own3 = pk2(sv[kb][rb+6], sv[kb][rb+7]);
            const u32 s0 = hi ? own0 : own2;
            const u32 s1 = hi ? own1 : own3;
            const u32 r0 = __shfl_xor(s0, 32, 64);
            const u32 r1 = __shfl_xor(s1, 32, 64);
            u32x4 pv;
            pv[0] = hi ? r0 : own0;
            pv[1] = hi ? r1 : own1;
            pv[2] = hi ? own2 : r0;
            pv[3] = hi ? own3 : r1;
            pw[kb*2 + half] = pv;
          }
        }
        // ---- O^T += V^T . P^T ----
        __builtin_amdgcn_s_setprio(1);
        #pragma unroll
        for (int db = 0; db < 2; db++){
          const int d = db*32 + lq;
          #pragma unroll
          for (int tt = 0; tt < 4; tt++){
            bf16x8 vf = *(const bf16x8*)&Vs[p][d][(tt*16 + hi*8) ^ ((d >> 3) * 8)];
            bf16x8 pfr = __builtin_bit_cast(bf16x8, pw[tt]);
            oacc[db] = __builtin_amdgcn_mfma_f32_32x32x16_bf16(vf, pfr, oacc[db], 0, 0, 0);
          }
        }
        __builtin_amdgcn_s_setprio(0);
      }

      // counted wait: stage(jt+1) [K in LDS + V regs] complete; stage(jt+2) stays in flight
      if (jt + 2 < NT) asm volatile("s_waitcnt vmcnt(4)" ::: "memory");
      else             asm volatile("s_waitcnt vmcnt(0)" ::: "memory");
      if (jt + 1 < NT) publishV(vvOther, p ^ 1);
      asm volatile("s_waitcnt lgkmcnt(0)" ::: "memory");
      __builtin_amdgcn_s_barrier();
    };

    #pragma unroll 1
    for (int jt2 = 0; jt2 < NT; jt2 += 2){
      body(jt2,     0, vvE, vvO);
      body(jt2 + 1, 1, vvO, vvE);
    }

    // ---- epilogue: lane owns q-row qrow; d = (r&3)+8*(r>>2)+4*hi + 32*db ----
    const float rl = 1.0f / lrun;
    u16* op = O + (size_t)(b*SS + qrow) * H + h * HD;
    #pragma unroll
    for (int db = 0; db < 2; db++)
      #pragma unroll
      for (int rq = 0; rq < 4; rq++){
        ushort4 o4;
        o4.x = f2bf(oacc[db][rq*4 + 0] * rl);
        o4.y = f2bf(oacc[db][rq*4 + 1] * rl);
        o4.z = f2bf(oacc[db][rq*4 + 2] * rl);
        o4.w = f2bf(oacc[db][rq*4 + 3] * rl);
        *(ushort4*)(op + db*32 + rq*8 + 4*hi) = o4;
      }
  }
}

extern "C" void kernel_launch(void* const* d_in, const int* in_sizes, int n_in,
                              void* d_out, int out_size, void* d_ws, size_t ws_size,
                              hipStream_t stream){
  (void)in_sizes; (void)n_in; (void)out_size; (void)ws_size;
  const float* hs = (const float*)d_in[0];
  // d_in[1] = attention_mask (causal, implemented analytically)
  const float* wq = (const float*)d_in[2];
  const float* wk = (const float*)d_in[3];
  const float* wv = (const float*)d_in[4];
  const float* wo = (const float*)d_in[5];
  float* out = (float*)d_out;
  char* ws = (char*)d_ws;

  // workspace layout (bytes): Xb 16.8M | Wqt/Wkt/Wvt/Wot 4x8.4M | Vb 16.8M | Ob 16.8M  (~80MB)
  u16* Xb  = (u16*)ws;
  u16* Wqt = (u16*)(ws + (size_t)MM * H * 2);
  u16* Wkt = Wqt + (size_t)H * H;
  u16* Wvt = Wkt + (size_t)H * H;
  u16* Wot = Wvt + (size_t)H * H;
  u16* Vb  = Wot + (size_t)H * H;
  u16* Ob  = Vb  + (size_t)MM * H;
  // Q,K (bf16) live in d_out's 33.5MB until the final GEMM overwrites it
  u16* Qb  = (u16*)d_out;
  u16* Kb  = Qb + (size_t)MM * H;

  k_cvt<<<8192, 256, 0, stream>>>(hs, Xb);
  k_wtrans<<<dim3(64, 64, 4), dim3(32, 8), 0, stream>>>(wq, wk, wv, wo, Wqt, Wkt, Wvt, Wot);
  k_gemm8<<<dim3(128, 3), 512, 0, stream>>>(Xb, Wqt, Wkt, Wvt, Qb, Kb, Vb, MM, H, H);
  k_rope<<<2048, 256, 0, stream>>>(Qb, Kb);
  k_attn<<<dim3(8, 64), 256, 0, stream>>>(Qb, Kb, Vb, Ob);
  k_gemm<float><<<dim3(32, 16, 1), 256, 0, stream>>>(Ob, Wot, Wot, Wot, out, out, out, MM, H, H);
}

// Round 7
// 298.086 us; speedup vs baseline: 1.0814x; 1.0814x over previous
//
#include <hip/hip_runtime.h>
#include <hip/hip_bf16.h>

#define H 2048
#define NH 32
#define HD 64
#define BB 2
#define SS 2048
#define MM (BB*SS)   // 4096 rows

typedef __attribute__((ext_vector_type(8))) short bf16x8;
typedef __attribute__((ext_vector_type(4))) float f32x4;
typedef __attribute__((ext_vector_type(16))) float f32x16;
typedef unsigned short u16;
typedef unsigned int u32;
typedef __attribute__((ext_vector_type(4))) u32 u32x4;

static __device__ __forceinline__ u16 f2bf(float f){
  union { float f; u32 i; } v; v.f = f;
  u32 x = v.i;
  return (u16)((x + 0x7FFFu + ((x >> 16) & 1u)) >> 16);  // RNE
}
static __device__ __forceinline__ float bf2f(u16 u){
  union { u32 i; float f; } v; v.i = ((u32)u) << 16; return v.f;
}
// packed f32x2 -> bf16x2 (low = a, high = b), single HW instr
static __device__ __forceinline__ u32 pk2(float a, float b){
  u32 r;
  asm("v_cvt_pk_bf16_f32 %0, %1, %2" : "=v"(r) : "v"(a), "v"(b));
  return r;
}

static __device__ __forceinline__ void gload16(const u16* g, u16* l){
  __builtin_amdgcn_global_load_lds((const __attribute__((address_space(1))) void*)g,
                                   (__attribute__((address_space(3))) void*)l, 16, 0, 0);
}

// ---------------- 1. X f32 -> bf16 ----------------
__global__ void k_cvt(const float* __restrict__ src, u16* __restrict__ dst){
  const int i = (blockIdx.x * 256 + threadIdx.x) * 4;
  float4 v = *(const float4*)(src + i);
  ushort4 o;
  o.x = f2bf(v.x); o.y = f2bf(v.y); o.z = f2bf(v.z); o.w = f2bf(v.w);
  *(ushort4*)(dst + i) = o;
}

// ---------------- 2. W [K][N] f32 -> Wt [N][K] bf16 ----------------
__global__ void k_wtrans(const float* __restrict__ w0, const float* __restrict__ w1,
                         const float* __restrict__ w2, const float* __restrict__ w3,
                         u16* __restrict__ d0, u16* __restrict__ d1,
                         u16* __restrict__ d2, u16* __restrict__ d3){
  __shared__ float tile[32][33];
  const int z = blockIdx.z;
  const float* w = z==0 ? w0 : z==1 ? w1 : z==2 ? w2 : w3;
  u16* d        = z==0 ? d0 : z==1 ? d1 : z==2 ? d2 : d3;
  const int n0 = blockIdx.x * 32, k0 = blockIdx.y * 32;
  const int tx = threadIdx.x, ty = threadIdx.y;  // 32 x 8
  #pragma unroll
  for (int j = 0; j < 4; j++)
    tile[ty + 8*j][tx] = w[(size_t)(k0 + ty + 8*j) * H + n0 + tx];
  __syncthreads();
  #pragma unroll
  for (int j = 0; j < 4; j++)
    d[(size_t)(n0 + ty + 8*j) * H + k0 + tx] = f2bf(tile[tx][ty + 8*j]);
}

// ---------------- 3. QKV GEMM, flattened N=6144: C = A[4096][2048] * Bt[6144][2048]^T ----------------
// BM=128 x BN=384 tiles -> grid 32x16 = 512 blocks = exactly 2 full dispatch
// rounds at 1 block/CU (128 KiB LDS). 512 thr = 8 waves (2M x 4N), per-wave
// 64x96 (acc[4][6]). BK=64, 2 LDS slots. Per K-tile: 4 phases {2 ds_read A-frags
// (+12 B-frags in ph0); setprio(1); 12 MFMA; setprio(0); barrier}; stage B(kt+2)
// after ph0 (B consumed in ph0), A(kt+2) after ph3; s_waitcnt vmcnt(8) counted
// (never drains mid-loop). Both-sides LDS swizzle col ^= (row&7)*8 (conflicts=0 in r6).
// Epilogue: per-column z = ncol>>11 selects Q/K/V destination.
__global__ __launch_bounds__(512, 2) void k_gemm8(
    const u16* __restrict__ A, const u16* __restrict__ Bt,
    u16* __restrict__ CQ, u16* __restrict__ CK, u16* __restrict__ CV,
    int M, int K){
  __shared__ __align__(16) u16 As[2][128][64];
  __shared__ __align__(16) u16 Bs[2][384][64];
  // XCD swizzle: 512 blocks, xcd = flat&7 owns 64 consecutive ids = 2 n-panels
  const int flat = blockIdx.x;
  const int id = (flat & 7) * 64 + (flat >> 3);
  const int gy = id >> 5, gx = id & 31;
  const int m0 = gx * 128, n0 = gy * 384;
  const int t = threadIdx.x, w = t >> 6, l = t & 63;
  const int wm = w >> 2, wn = w & 3;           // wave rows wm*64.., cols wn*96..
  const int lrow = l & 15, lk = (l >> 4) * 8;
  const int sw = (lrow & 7) * 8;               // read-side swizzle
  const int sr = t >> 3, sc = (t & 7) * 8;     // staging lane pattern (lds = base + lane*16)
  const int ssc = sc ^ ((sr & 7) * 8);         // pre-swizzled global col
  const int NK = K >> 6;

  auto stageA = [&](int kt, int u){
    const size_t kb = (size_t)kt * 64 + ssc;
    #pragma unroll
    for (int c = 0; c < 2; c++)
      gload16(A + (size_t)(m0 + c*64 + sr) * K + kb, &As[u][c*64 + sr][sc]);
  };
  auto stageB = [&](int kt, int u){
    const size_t kb = (size_t)kt * 64 + ssc;
    #pragma unroll
    for (int c = 0; c < 6; c++)
      gload16(Bt + (size_t)(n0 + c*64 + sr) * K + kb, &Bs[u][c*64 + sr][sc]);
  };

  f32x4 acc[4][6] = {};

  // prologue: stage tiles 0 and 1; wait tile 0 (tile 1 stays in flight)
  stageA(0, 0); stageB(0, 0);
  stageA(1, 1); stageB(1, 1);
  asm volatile("s_waitcnt vmcnt(8)" ::: "memory");
  __builtin_amdgcn_s_barrier();

  #pragma unroll 1
  for (int kt = 0; kt < NK; ++kt){
    const int u = kt & 1;
    const bool more = (kt + 2 < NK);

    // ---- phase 0: all B-frags + A m-block 0, then 12 MFMA ----
    bf16x8 bfr[6][2];
    #pragma unroll
    for (int n = 0; n < 6; n++){
      const int row = wn*96 + n*16 + lrow;
      bfr[n][0] = *(const bf16x8*)&Bs[u][row][lk ^ sw];
      bfr[n][1] = *(const bf16x8*)&Bs[u][row][(32 + lk) ^ sw];
    }
    {
      const int ar = wm*64 + lrow;
      bf16x8 a0 = *(const bf16x8*)&As[u][ar][lk ^ sw];
      bf16x8 a1 = *(const bf16x8*)&As[u][ar][(32 + lk) ^ sw];
      __builtin_amdgcn_s_setprio(1);
      #pragma unroll
      for (int n = 0; n < 6; n++){
        acc[0][n] = __builtin_amdgcn_mfma_f32_16x16x32_bf16(a0, bfr[n][0], acc[0][n], 0, 0, 0);
        acc[0][n] = __builtin_amdgcn_mfma_f32_16x16x32_bf16(a1, bfr[n][1], acc[0][n], 0, 0, 0);
      }
      __builtin_amdgcn_s_setprio(0);
    }
    __builtin_amdgcn_s_barrier();
    if (more) stageB(kt + 2, u);   // Bs[u] fully consumed in phase 0

    // ---- phases 1..3: A m-blocks 1..3 ----
    #pragma unroll
    for (int mb = 1; mb < 4; mb++){
      const int ar = wm*64 + mb*16 + lrow;
      bf16x8 a0 = *(const bf16x8*)&As[u][ar][lk ^ sw];
      bf16x8 a1 = *(const bf16x8*)&As[u][ar][(32 + lk) ^ sw];
      __builtin_amdgcn_s_setprio(1);
      #pragma unroll
      for (int n = 0; n < 6; n++){
        acc[mb][n] = __builtin_amdgcn_mfma_f32_16x16x32_bf16(a0, bfr[n][0], acc[mb][n], 0, 0, 0);
        acc[mb][n] = __builtin_amdgcn_mfma_f32_16x16x32_bf16(a1, bfr[n][1], acc[mb][n], 0, 0, 0);
      }
      __builtin_amdgcn_s_setprio(0);
      __builtin_amdgcn_s_barrier();
    }

    // ---- tail: stage A(kt+2) into freed slot, counted wait for tile kt+1 ----
    if (more){
      stageA(kt + 2, u);
      asm volatile("s_waitcnt vmcnt(8)" ::: "memory");   // kt+1 landed; kt+2's 8 in flight
      __builtin_amdgcn_s_barrier();
    } else if (kt + 1 < NK){
      asm volatile("s_waitcnt vmcnt(0)" ::: "memory");   // final tile landed
      __builtin_amdgcn_s_barrier();
    }
  }

  // ---- epilogue: per-column z-select (tiles straddle the 2048-col boundaries) ----
  #pragma unroll
  for (int m = 0; m < 4; m++)
    #pragma unroll
    for (int n = 0; n < 6; n++){
      const int ncol = n0 + wn*96 + n*16 + lrow;
      const int z = ncol >> 11;
      u16* C = (z == 0 ? CQ : z == 1 ? CK : CV) + (ncol & 2047);
      #pragma unroll
      for (int r = 0; r < 4; r++){
        const int row = m0 + wm*64 + m*16 + (l >> 4)*4 + r;
        C[(size_t)row * H] = f2bf(acc[m][n][r]);
      }
    }
}

// ---------------- 3b/6. GEMM C[M][N] = A[M][K] * Bt[N][K]^T (128^2, out-proj) ----------------
template<typename OutT>
__global__ __launch_bounds__(256, 2) void k_gemm(
    const u16* __restrict__ A,
    const u16* __restrict__ B0, const u16* __restrict__ B1, const u16* __restrict__ B2,
    OutT* __restrict__ C0, OutT* __restrict__ C1, OutT* __restrict__ C2,
    int M, int N, int K){
  __shared__ __align__(16) u16 As[128][64];
  __shared__ __align__(16) u16 Bs[128][64];
  const int z = blockIdx.z;
  const u16* Bt = z==0 ? B0 : z==1 ? B1 : B2;
  OutT* C       = z==0 ? C0 : z==1 ? C1 : C2;
  const int t = threadIdx.x;
  const int w = t >> 6, l = t & 63;
  const int m0 = blockIdx.x * 128, n0 = blockIdx.y * 128;
  const int srow = t >> 3, scol = (t & 7) * 8;      // staging: 32 rows x 8 chunks
  const int lrow = l & 15, lk = (l >> 4) * 8;       // fragment lane mapping
  const int wr = (w >> 1) * 64, wc = (w & 1) * 64;  // wave tile
  f32x4 acc[4][4] = {};
  for (int k0 = 0; k0 < K; k0 += 64){
    __syncthreads();
    #pragma unroll
    for (int c = 0; c < 4; c++)
      gload16(A + (size_t)(m0 + c*32 + srow) * K + k0 + scol, &As[c*32 + srow][scol]);
    #pragma unroll
    for (int c = 0; c < 4; c++)
      gload16(Bt + (size_t)(n0 + c*32 + srow) * K + k0 + scol, &Bs[c*32 + srow][scol]);
    __syncthreads();
    #pragma unroll
    for (int kk = 0; kk < 2; kk++){
      bf16x8 a[4], b[4];
      #pragma unroll
      for (int m = 0; m < 4; m++) a[m] = *(const bf16x8*)&As[wr + m*16 + lrow][kk*32 + lk];
      #pragma unroll
      for (int n = 0; n < 4; n++) b[n] = *(const bf16x8*)&Bs[wc + n*16 + lrow][kk*32 + lk];
      #pragma unroll
      for (int m = 0; m < 4; m++)
        #pragma unroll
        for (int n = 0; n < 4; n++)
          acc[m][n] = __builtin_amdgcn_mfma_f32_16x16x32_bf16(a[m], b[n], acc[m][n], 0, 0, 0);
    }
  }
  #pragma unroll
  for (int m = 0; m < 4; m++)
    #pragma unroll
    for (int n = 0; n < 4; n++)
      #pragma unroll
      for (int r = 0; r < 4; r++){
        const int row = m0 + wr + m*16 + (l >> 4)*4 + r;
        const int col = n0 + wc + n*16 + lrow;
        const float v = acc[m][n][r];
        if constexpr (sizeof(OutT) == 2) C[(size_t)row * N + col] = (OutT)f2bf(v);
        else                             C[(size_t)row * N + col] = v;
      }
}

// ---------------- 4. RoPE on Q and K, in place ----------------
// Q additionally scaled by log2(e)/sqrt(HD) so attention can use exp2 directly.
__global__ void k_rope(u16* __restrict__ Q, u16* __restrict__ Kp){
  const int idx = blockIdx.x * 256 + threadIdx.x;  // 4096*32*4 threads
  const int quad = idx & 3;
  const int h = (idx >> 2) & 31;
  const int row = idx >> 7;
  const int s = row & (SS - 1);
  const int i0 = quad * 8;
  u16* q = Q  + (size_t)row * H + h * HD;
  u16* k = Kp + (size_t)row * H + h * HD;
  uint4 q1v = *(const uint4*)(q + i0);
  uint4 q2v = *(const uint4*)(q + i0 + 32);
  uint4 k1v = *(const uint4*)(k + i0);
  uint4 k2v = *(const uint4*)(k + i0 + 32);
  u16* q1 = (u16*)&q1v; u16* q2 = (u16*)&q2v;
  u16* k1 = (u16*)&k1v; u16* k2 = (u16*)&k2v;
  const float sf = (float)s;
  const float QSC = 0.18033688011112042f;  // (1/8) * log2(e)
  #pragma unroll
  for (int e = 0; e < 8; e++){
    const int i = i0 + e;
    const float inv = exp2f(-0.4152410118609203f * (float)i);  // 10000^(-i/32)
    float rev = sf * inv * 0.15915494309189535f;               // radians -> revolutions
    rev -= floorf(rev);
    const float sn = __builtin_amdgcn_sinf(rev);
    const float cs = __builtin_amdgcn_cosf(rev);
    const float qa = bf2f(q1[e]), qb = bf2f(q2[e]);
    q1[e] = f2bf((qa*cs - qb*sn) * QSC);
    q2[e] = f2bf((qb*cs + qa*sn) * QSC);
    const float ka = bf2f(k1[e]), kb = bf2f(k2[e]);
    k1[e] = f2bf(ka*cs - kb*sn);
    k2[e] = f2bf(kb*cs + ka*sn);
  }
  *(uint4*)(q + i0)      = q1v;
  *(uint4*)(q + i0 + 32) = q2v;
  *(uint4*)(k + i0)      = k1v;
  *(uint4*)(k + i0 + 32) = k2v;
}

// ---------------- 5. causal flash attention (swapped QK^T, 32x32 mfma) ----------------
// block = 256 thr (4 waves x 32 q-rows = 128 q/block). Block x handles q-tiles
// {15-x, x} -> uniform 36 KV-iterations. Counted-vmcnt pipeline (T4): stage
// tile t+2 each iter; s_waitcnt vmcnt(4) + raw s_barrier (NO vmcnt(0) drain).
// K: 3 LDS buffers via global_load_lds; V: 2-deep reg prefetch -> transposed LDS.
__global__ __launch_bounds__(256, 2) void k_attn(
    const u16* __restrict__ Q, const u16* __restrict__ K,
    const u16* __restrict__ V, u16* __restrict__ O){
  __shared__ __align__(16) u16 Ks[3][64][64];   // swizzled: col ^ (row&7)*8
  __shared__ __align__(16) u16 Vs[2][64][72];   // transposed Vs[d][j], j ^ (d>>3)*8
  const int t = threadIdx.x, w = t >> 6, l = t & 63;
  const int x = blockIdx.x, bh = blockIdx.y;
  const int b = bh >> 5, h = bh & 31;
  const u16* kp = K + (size_t)(b*SS) * H + h * HD;
  const u16* vp = V + (size_t)(b*SS) * H + h * HD;
  const int sr = t >> 3, sc = (t & 7) * 8;      // staging: linear-LDS pattern
  const int ssc = sc ^ ((sr & 7) * 8);          // pre-swizzled global col for K
  const int hi = l >> 5, lq = l & 31;

  auto stageK = [&](int tile, int buf){
    const int jb = tile * 64;
    gload16(kp + (size_t)(jb + sr) * H + ssc,      &Ks[buf][sr][sc]);
    gload16(kp + (size_t)(jb + 32 + sr) * H + ssc, &Ks[buf][32 + sr][sc]);
  };
  auto loadV = [&](int tile, uint4* vv){
    const int jb = tile * 64;
    vv[0] = *(const uint4*)(vp + (size_t)(jb + sr) * H + sc);
    vv[1] = *(const uint4*)(vp + (size_t)(jb + 32 + sr) * H + sc);
  };
  auto publishV = [&](const uint4* vv, int buf){
    #pragma unroll
    for (int c = 0; c < 2; c++){
      const int j = c*32 + sr;
      const u16* pv = (const u16*)&vv[c];
      #pragma unroll
      for (int e = 0; e < 8; e++){
        const int d = sc + e;
        Vs[buf][d][j ^ ((d >> 3) * 8)] = pv[e];
      }
    }
  };

  #pragma unroll 1
  for (int pp = 0; pp < 2; pp++){
    const int qt = pp ? x : (15 - x);           // heavy pass first
    const int NT = 2*qt + 2;                    // even
    const int qw0 = qt*128 + w*32;
    const int qrow = qw0 + lq;                  // this lane's q index

    // Q fragments (B-operand of swapped QK^T): lane holds Q[qrow][c*16 + hi*8 + e]
    const u16* qptr = Q + (size_t)(b*SS + qrow) * H + h * HD + hi*8;
    bf16x8 qf[4];
    #pragma unroll
    for (int c = 0; c < 4; c++) qf[c] = *(const bf16x8*)(qptr + c*16);

    float mrun = -1e30f, lrun = 0.f;
    f32x16 oacc[2] = {};
    uint4 vvE[2], vvO[2];

    // ---- prologue: stage tiles 0 (->vvE) and 1 (->vvO) ----
    stageK(0, 0); loadV(0, vvE);
    stageK(1, 1); loadV(1, vvO);
    asm volatile("s_waitcnt vmcnt(4)" ::: "memory");   // stage(0) complete
    publishV(vvE, 0);
    asm volatile("s_waitcnt lgkmcnt(0)" ::: "memory");
    __builtin_amdgcn_s_barrier();

    // one pipelined body; p = jt&1 (compile-time at call site)
    auto body = [&](int jt, int p, uint4* vvSelf, const uint4* vvOther){
      const int j0 = jt * 64;
      if (jt + 2 < NT){ stageK(jt + 2, (jt + 2) % 3); loadV(jt + 2, vvSelf); }

      if (j0 <= qw0){   // wave has live rows in this tile
        const int kbuf = jt % 3;
        // ---- S^T = K . Q^T ----
        f32x16 sv[2] = {};
        __builtin_amdgcn_s_setprio(1);
        #pragma unroll
        for (int kb = 0; kb < 2; kb++){
          const int row = kb*32 + lq;
          #pragma unroll
          for (int c = 0; c < 4; c++){
            bf16x8 kf = *(const bf16x8*)&Ks[kbuf][row][(c*16 + hi*8) ^ ((row & 7) * 8)];
            sv[kb] = __builtin_amdgcn_mfma_f32_32x32x16_bf16(kf, qf[c], sv[kb], 0, 0, 0);
          }
        }
        __builtin_amdgcn_s_setprio(0);
        // ---- causal mask (diagonal-touching tiles only) ----
        if (j0 + 63 > qw0){
          #pragma unroll
          for (int kb = 0; kb < 2; kb++)
            #pragma unroll
            for (int r = 0; r < 16; r++){
              const int kg = j0 + kb*32 + (r & 3) + 8*(r >> 2) + 4*hi;
              if (kg > qrow) sv[kb][r] = -1e30f;
            }
        }
        // ---- online softmax (exp2 domain), tree reduce, partner lane l^32 ----
        float t16[16], t8[8], t4[4];
        #pragma unroll
        for (int r = 0; r < 16; r++) t16[r] = fmaxf(sv[0][r], sv[1][r]);
        #pragma unroll
        for (int r = 0; r < 8; r++) t8[r] = fmaxf(t16[r], t16[r+8]);
        #pragma unroll
        for (int r = 0; r < 4; r++) t4[r] = fmaxf(t8[r], t8[r+4]);
        float tm = fmaxf(fmaxf(t4[0], t4[2]), fmaxf(t4[1], t4[3]));
        tm = fmaxf(tm, __shfl_xor(tm, 32, 64));
        if (__any(tm > mrun)){       // exact: skipped iff fac == 1.0 for all lanes
          const float mn = fmaxf(mrun, tm);
          const float fac = exp2f(mrun - mn);
          mrun = mn;
          lrun *= fac;
          #pragma unroll
          for (int db = 0; db < 2; db++)
            #pragma unroll
            for (int r = 0; r < 16; r++) oacc[db][r] *= fac;
        }
        #pragma unroll
        for (int kb = 0; kb < 2; kb++)
          #pragma unroll
          for (int r = 0; r < 16; r++) sv[kb][r] = exp2f(sv[kb][r] - mrun);
        float s16[16], s8[8], s4[4];
        #pragma unroll
        for (int r = 0; r < 16; r++) s16[r] = sv[0][r] + sv[1][r];
        #pragma unroll
        for (int r = 0; r < 8; r++) s8[r] = s16[r] + s16[r+8];
        #pragma unroll
        for (int r = 0; r < 4; r++) s4[r] = s8[r] + s8[r+4];
        float rs = (s4[0] + s4[1]) + (s4[2] + s4[3]);
        rs += __shfl_xor(rs, 32, 64);
        lrun += rs;
        // ---- build PV B-frags: cvt_pk pairs, exchange halves via xor-32 ----
        u32x4 pw[4];
        #pragma unroll
        for (int kb = 0; kb < 2; kb++){
          #pragma unroll
          for (int half = 0; half < 2; half++){
            const int rb = half * 8;
            const u32 own0 = pk2(sv[kb][rb+0], sv[kb][rb+1]);
            const u32 own1 = pk2(sv[kb][rb+2], sv[kb][rb+3]);
            const u32 own2 = pk2(sv[kb][rb+4], sv[kb][rb+5]);
            const u32 own3 = pk2(sv[kb][rb+6], sv[kb][rb+7]);
            const u32 s0 = hi ? own0 : own2;
            const u32 s1 = hi ? own1 : own3;
            const u32 r0 = __shfl_xor(s0, 32, 64);
            const u32 r1 = __shfl_xor(s1, 32, 64);
            u32x4 pv;
            pv[0] = hi ? r0 : own0;
            pv[1] = hi ? r1 : own1;
            pv[2] = hi ? own2 : r0;
            pv[3] = hi ? own3 : r1;
            pw[kb*2 + half] = pv;
          }
        }
        // ---- O^T += V^T . P^T ----
        __builtin_amdgcn_s_setprio(1);
        #pragma unroll
        for (int db = 0; db < 2; db++){
          const int d = db*32 + lq;
          #pragma unroll
          for (int tt = 0; tt < 4; tt++){
            bf16x8 vf = *(const bf16x8*)&Vs[p][d][(tt*16 + hi*8) ^ ((d >> 3) * 8)];
            bf16x8 pfr = __builtin_bit_cast(bf16x8, pw[tt]);
            oacc[db] = __builtin_amdgcn_mfma_f32_32x32x16_bf16(vf, pfr, oacc[db], 0, 0, 0);
          }
        }
        __builtin_amdgcn_s_setprio(0);
      }

      // counted wait: stage(jt+1) [K in LDS + V regs] complete; stage(jt+2) stays in flight
      if (jt + 2 < NT) asm volatile("s_waitcnt vmcnt(4)" ::: "memory");
      else             asm volatile("s_waitcnt vmcnt(0)" ::: "memory");
      if (jt + 1 < NT) publishV(vvOther, p ^ 1);
      asm volatile("s_waitcnt lgkmcnt(0)" ::: "memory");
      __builtin_amdgcn_s_barrier();
    };

    #pragma unroll 1
    for (int jt2 = 0; jt2 < NT; jt2 += 2){
      body(jt2,     0, vvE, vvO);
      body(jt2 + 1, 1, vvO, vvE);
    }

    // ---- epilogue: lane owns q-row qrow; d = (r&3)+8*(r>>2)+4*hi + 32*db ----
    const float rl = 1.0f / lrun;
    u16* op = O + (size_t)(b*SS + qrow) * H + h * HD;
    #pragma unroll
    for (int db = 0; db < 2; db++)
      #pragma unroll
      for (int rq = 0; rq < 4; rq++){
        ushort4 o4;
        o4.x = f2bf(oacc[db][rq*4 + 0] * rl);
        o4.y = f2bf(oacc[db][rq*4 + 1] * rl);
        o4.z = f2bf(oacc[db][rq*4 + 2] * rl);
        o4.w = f2bf(oacc[db][rq*4 + 3] * rl);
        *(ushort4*)(op + db*32 + rq*8 + 4*hi) = o4;
      }
  }
}

extern "C" void kernel_launch(void* const* d_in, const int* in_sizes, int n_in,
                              void* d_out, int out_size, void* d_ws, size_t ws_size,
                              hipStream_t stream){
  (void)in_sizes; (void)n_in; (void)out_size; (void)ws_size;
  const float* hs = (const float*)d_in[0];
  // d_in[1] = attention_mask (causal, implemented analytically)
  const float* wq = (const float*)d_in[2];
  const float* wk = (const float*)d_in[3];
  const float* wv = (const float*)d_in[4];
  const float* wo = (const float*)d_in[5];
  float* out = (float*)d_out;
  char* ws = (char*)d_ws;

  // workspace layout (bytes): Xb 16.8M | Wqt/Wkt/Wvt (contiguous, = flattened
  // Bt[6144][2048]) + Wot 4x8.4M | Vb 16.8M | Ob 16.8M  (~84MB)
  u16* Xb  = (u16*)ws;
  u16* Wqt = (u16*)(ws + (size_t)MM * H * 2);
  u16* Wkt = Wqt + (size_t)H * H;
  u16* Wvt = Wkt + (size_t)H * H;
  u16* Wot = Wvt + (size_t)H * H;
  u16* Vb  = Wot + (size_t)H * H;
  u16* Ob  = Vb  + (size_t)MM * H;
  // Q,K (bf16) live in d_out's 33.5MB until the final GEMM overwrites it
  u16* Qb  = (u16*)d_out;
  u16* Kb  = Qb + (size_t)MM * H;

  k_cvt<<<8192, 256, 0, stream>>>(hs, Xb);
  k_wtrans<<<dim3(64, 64, 4), dim3(32, 8), 0, stream>>>(wq, wk, wv, wo, Wqt, Wkt, Wvt, Wot);
  k_gemm8<<<512, 512, 0, stream>>>(Xb, Wqt, Qb, Kb, Vb, MM, H);
  k_rope<<<2048, 256, 0, stream>>>(Qb, Kb);
  k_attn<<<dim3(8, 64), 256, 0, stream>>>(Qb, Kb, Vb, Ob);
  k_gemm<float><<<dim3(32, 16, 1), 256, 0, stream>>>(Ob, Wot, Wot, Wot, out, out, out, MM, H, H);
}

// Round 8
// 295.990 us; speedup vs baseline: 1.0891x; 1.0071x over previous
//
#include <hip/hip_runtime.h>
#include <hip/hip_bf16.h>

#define H 2048
#define NH 32
#define HD 64
#define BB 2
#define SS 2048
#define MM (BB*SS)   // 4096 rows

typedef __attribute__((ext_vector_type(8))) short bf16x8;
typedef __attribute__((ext_vector_type(4))) float f32x4;
typedef __attribute__((ext_vector_type(16))) float f32x16;
typedef unsigned short u16;
typedef unsigned int u32;
typedef __attribute__((ext_vector_type(4))) u32 u32x4;

static __device__ __forceinline__ u16 f2bf(float f){
  union { float f; u32 i; } v; v.f = f;
  u32 x = v.i;
  return (u16)((x + 0x7FFFu + ((x >> 16) & 1u)) >> 16);  // RNE
}
static __device__ __forceinline__ float bf2f(u16 u){
  union { u32 i; float f; } v; v.i = ((u32)u) << 16; return v.f;
}
// packed f32x2 -> bf16x2 (low = a, high = b), single HW instr
static __device__ __forceinline__ u32 pk2(float a, float b){
  u32 r;
  asm("v_cvt_pk_bf16_f32 %0, %1, %2" : "=v"(r) : "v"(a), "v"(b));
  return r;
}

static __device__ __forceinline__ void gload16(const u16* g, u16* l){
  __builtin_amdgcn_global_load_lds((const __attribute__((address_space(1))) void*)g,
                                   (__attribute__((address_space(3))) void*)l, 16, 0, 0);
}

// ---------------- 1. X f32 -> bf16 ----------------
__global__ void k_cvt(const float* __restrict__ src, u16* __restrict__ dst){
  const int i = (blockIdx.x * 256 + threadIdx.x) * 4;
  float4 v = *(const float4*)(src + i);
  ushort4 o;
  o.x = f2bf(v.x); o.y = f2bf(v.y); o.z = f2bf(v.z); o.w = f2bf(v.w);
  *(ushort4*)(dst + i) = o;
}

// ---------------- 2. W [K][N] f32 -> Wt [N][K] bf16 ----------------
__global__ void k_wtrans(const float* __restrict__ w0, const float* __restrict__ w1,
                         const float* __restrict__ w2, const float* __restrict__ w3,
                         u16* __restrict__ d0, u16* __restrict__ d1,
                         u16* __restrict__ d2, u16* __restrict__ d3){
  __shared__ float tile[32][33];
  const int z = blockIdx.z;
  const float* w = z==0 ? w0 : z==1 ? w1 : z==2 ? w2 : w3;
  u16* d        = z==0 ? d0 : z==1 ? d1 : z==2 ? d2 : d3;
  const int n0 = blockIdx.x * 32, k0 = blockIdx.y * 32;
  const int tx = threadIdx.x, ty = threadIdx.y;  // 32 x 8
  #pragma unroll
  for (int j = 0; j < 4; j++)
    tile[ty + 8*j][tx] = w[(size_t)(k0 + ty + 8*j) * H + n0 + tx];
  __syncthreads();
  #pragma unroll
  for (int j = 0; j < 4; j++)
    d[(size_t)(n0 + ty + 8*j) * H + k0 + tx] = f2bf(tile[tx][ty + 8*j]);
}

// ---------------- 3. QKV GEMM, flattened N=6144: C = A[4096][2048] * Bt[6144][2048]^T ----------------
// BM=128 x BN=384 tiles -> grid 32x16 = 512 blocks = exactly 2 full dispatch
// rounds at 1 block/CU (128 KiB LDS). 512 thr = 8 waves (2M x 4N), per-wave
// 64x96 (acc[4][6]). BK=64, 2 LDS slots.
// BALANCED 4-phase K-tile (m201 interleave at this tile shape):
//   p0: read B kh0 (6 b128) + A mb{0,1} kh0 (2) -> 12 MFMA -> barrier
//   p1: read B kh1 (6)      + A mb{0,1} kh1 (2) -> 12 MFMA -> barrier  [B slot consumed]
//   p2: stage B(kt+2) (6 gload) ; read A mb{2,3} kh0 (2) -> 12 MFMA (b0 regs) -> barrier
//   p3: read A mb{2,3} kh1 (2) -> 12 MFMA (b1 regs) -> barrier
//   tail: stage A(kt+2) (2 gload); s_waitcnt vmcnt(8) counted (never drains mid-loop); barrier
// Both-sides LDS swizzle col ^= (row&7)*8 (conflicts measured 0).
// Epilogue: per-column z = ncol>>11 selects Q/K/V destination.
__global__ __launch_bounds__(512, 2) void k_gemm8(
    const u16* __restrict__ A, const u16* __restrict__ Bt,
    u16* __restrict__ CQ, u16* __restrict__ CK, u16* __restrict__ CV,
    int M, int K){
  __shared__ __align__(16) u16 As[2][128][64];
  __shared__ __align__(16) u16 Bs[2][384][64];
  // XCD swizzle: 512 blocks, xcd = flat&7 owns 64 consecutive ids = 2 n-panels
  const int flat = blockIdx.x;
  const int id = (flat & 7) * 64 + (flat >> 3);
  const int gy = id >> 5, gx = id & 31;
  const int m0 = gx * 128, n0 = gy * 384;
  const int t = threadIdx.x, w = t >> 6, l = t & 63;
  const int wm = w >> 2, wn = w & 3;           // wave rows wm*64.., cols wn*96..
  const int lrow = l & 15, lk = (l >> 4) * 8;
  const int sw = (lrow & 7) * 8;               // read-side swizzle
  const int sr = t >> 3, sc = (t & 7) * 8;     // staging lane pattern (lds = base + lane*16)
  const int ssc = sc ^ ((sr & 7) * 8);         // pre-swizzled global col
  const int NK = K >> 6;

  auto stageA = [&](int kt, int u){
    const size_t kb = (size_t)kt * 64 + ssc;
    #pragma unroll
    for (int c = 0; c < 2; c++)
      gload16(A + (size_t)(m0 + c*64 + sr) * K + kb, &As[u][c*64 + sr][sc]);
  };
  auto stageB = [&](int kt, int u){
    const size_t kb = (size_t)kt * 64 + ssc;
    #pragma unroll
    for (int c = 0; c < 6; c++)
      gload16(Bt + (size_t)(n0 + c*64 + sr) * K + kb, &Bs[u][c*64 + sr][sc]);
  };

  f32x4 acc[4][6] = {};

  // prologue: stage tiles 0 and 1; wait tile 0 (tile 1 stays in flight)
  stageA(0, 0); stageB(0, 0);
  stageA(1, 1); stageB(1, 1);
  asm volatile("s_waitcnt vmcnt(8)" ::: "memory");
  __builtin_amdgcn_s_barrier();

  #pragma unroll 1
  for (int kt = 0; kt < NK; ++kt){
    const int u = kt & 1;
    const bool more = (kt + 2 < NK);
    bf16x8 b0[6], b1[6], a0, a1;

    // ---- phase 0: B kh0 + A mb{0,1} kh0 -> 12 MFMA ----
    #pragma unroll
    for (int n = 0; n < 6; n++)
      b0[n] = *(const bf16x8*)&Bs[u][wn*96 + n*16 + lrow][lk ^ sw];
    a0 = *(const bf16x8*)&As[u][wm*64 +  0 + lrow][lk ^ sw];
    a1 = *(const bf16x8*)&As[u][wm*64 + 16 + lrow][lk ^ sw];
    __builtin_amdgcn_s_setprio(1);
    #pragma unroll
    for (int n = 0; n < 6; n++){
      acc[0][n] = __builtin_amdgcn_mfma_f32_16x16x32_bf16(a0, b0[n], acc[0][n], 0, 0, 0);
      acc[1][n] = __builtin_amdgcn_mfma_f32_16x16x32_bf16(a1, b0[n], acc[1][n], 0, 0, 0);
    }
    __builtin_amdgcn_s_setprio(0);
    __builtin_amdgcn_s_barrier();

    // ---- phase 1: B kh1 + A mb{0,1} kh1 -> 12 MFMA  [B slot fully consumed] ----
    #pragma unroll
    for (int n = 0; n < 6; n++)
      b1[n] = *(const bf16x8*)&Bs[u][wn*96 + n*16 + lrow][(32 + lk) ^ sw];
    a0 = *(const bf16x8*)&As[u][wm*64 +  0 + lrow][(32 + lk) ^ sw];
    a1 = *(const bf16x8*)&As[u][wm*64 + 16 + lrow][(32 + lk) ^ sw];
    __builtin_amdgcn_s_setprio(1);
    #pragma unroll
    for (int n = 0; n < 6; n++){
      acc[0][n] = __builtin_amdgcn_mfma_f32_16x16x32_bf16(a0, b1[n], acc[0][n], 0, 0, 0);
      acc[1][n] = __builtin_amdgcn_mfma_f32_16x16x32_bf16(a1, b1[n], acc[1][n], 0, 0, 0);
    }
    __builtin_amdgcn_s_setprio(0);
    __builtin_amdgcn_s_barrier();

    // ---- phase 2: stage B(kt+2) into freed B slot; A mb{2,3} kh0 -> 12 MFMA ----
    if (more) stageB(kt + 2, u);
    a0 = *(const bf16x8*)&As[u][wm*64 + 32 + lrow][lk ^ sw];
    a1 = *(const bf16x8*)&As[u][wm*64 + 48 + lrow][lk ^ sw];
    __builtin_amdgcn_s_setprio(1);
    #pragma unroll
    for (int n = 0; n < 6; n++){
      acc[2][n] = __builtin_amdgcn_mfma_f32_16x16x32_bf16(a0, b0[n], acc[2][n], 0, 0, 0);
      acc[3][n] = __builtin_amdgcn_mfma_f32_16x16x32_bf16(a1, b0[n], acc[3][n], 0, 0, 0);
    }
    __builtin_amdgcn_s_setprio(0);
    __builtin_amdgcn_s_barrier();

    // ---- phase 3: A mb{2,3} kh1 -> 12 MFMA ----
    a0 = *(const bf16x8*)&As[u][wm*64 + 32 + lrow][(32 + lk) ^ sw];
    a1 = *(const bf16x8*)&As[u][wm*64 + 48 + lrow][(32 + lk) ^ sw];
    __builtin_amdgcn_s_setprio(1);
    #pragma unroll
    for (int n = 0; n < 6; n++){
      acc[2][n] = __builtin_amdgcn_mfma_f32_16x16x32_bf16(a0, b1[n], acc[2][n], 0, 0, 0);
      acc[3][n] = __builtin_amdgcn_mfma_f32_16x16x32_bf16(a1, b1[n], acc[3][n], 0, 0, 0);
    }
    __builtin_amdgcn_s_setprio(0);
    __builtin_amdgcn_s_barrier();   // A slot fully consumed

    // ---- tail: stage A(kt+2), counted wait for tile kt+1 ----
    if (more){
      stageA(kt + 2, u);
      asm volatile("s_waitcnt vmcnt(8)" ::: "memory");   // kt+1 landed; kt+2's 8 in flight
      __builtin_amdgcn_s_barrier();
    } else if (kt + 1 < NK){
      asm volatile("s_waitcnt vmcnt(0)" ::: "memory");   // final tile landed
      __builtin_amdgcn_s_barrier();
    }
  }

  // ---- epilogue: per-column z-select (tiles straddle the 2048-col boundaries) ----
  #pragma unroll
  for (int m = 0; m < 4; m++)
    #pragma unroll
    for (int n = 0; n < 6; n++){
      const int ncol = n0 + wn*96 + n*16 + lrow;
      const int z = ncol >> 11;
      u16* C = (z == 0 ? CQ : z == 1 ? CK : CV) + (ncol & 2047);
      #pragma unroll
      for (int r = 0; r < 4; r++){
        const int row = m0 + wm*64 + m*16 + (l >> 4)*4 + r;
        C[(size_t)row * H] = f2bf(acc[m][n][r]);
      }
    }
}

// ---------------- 3b/6. GEMM C[M][N] = A[M][K] * Bt[N][K]^T (128^2, out-proj) ----------------
template<typename OutT>
__global__ __launch_bounds__(256, 2) void k_gemm(
    const u16* __restrict__ A,
    const u16* __restrict__ B0, const u16* __restrict__ B1, const u16* __restrict__ B2,
    OutT* __restrict__ C0, OutT* __restrict__ C1, OutT* __restrict__ C2,
    int M, int N, int K){
  __shared__ __align__(16) u16 As[128][64];
  __shared__ __align__(16) u16 Bs[128][64];
  const int z = blockIdx.z;
  const u16* Bt = z==0 ? B0 : z==1 ? B1 : B2;
  OutT* C       = z==0 ? C0 : z==1 ? C1 : C2;
  const int t = threadIdx.x;
  const int w = t >> 6, l = t & 63;
  const int m0 = blockIdx.x * 128, n0 = blockIdx.y * 128;
  const int srow = t >> 3, scol = (t & 7) * 8;      // staging: 32 rows x 8 chunks
  const int lrow = l & 15, lk = (l >> 4) * 8;       // fragment lane mapping
  const int wr = (w >> 1) * 64, wc = (w & 1) * 64;  // wave tile
  f32x4 acc[4][4] = {};
  for (int k0 = 0; k0 < K; k0 += 64){
    __syncthreads();
    #pragma unroll
    for (int c = 0; c < 4; c++)
      gload16(A + (size_t)(m0 + c*32 + srow) * K + k0 + scol, &As[c*32 + srow][scol]);
    #pragma unroll
    for (int c = 0; c < 4; c++)
      gload16(Bt + (size_t)(n0 + c*32 + srow) * K + k0 + scol, &Bs[c*32 + srow][scol]);
    __syncthreads();
    #pragma unroll
    for (int kk = 0; kk < 2; kk++){
      bf16x8 a[4], b[4];
      #pragma unroll
      for (int m = 0; m < 4; m++) a[m] = *(const bf16x8*)&As[wr + m*16 + lrow][kk*32 + lk];
      #pragma unroll
      for (int n = 0; n < 4; n++) b[n] = *(const bf16x8*)&Bs[wc + n*16 + lrow][kk*32 + lk];
      #pragma unroll
      for (int m = 0; m < 4; m++)
        #pragma unroll
        for (int n = 0; n < 4; n++)
          acc[m][n] = __builtin_amdgcn_mfma_f32_16x16x32_bf16(a[m], b[n], acc[m][n], 0, 0, 0);
    }
  }
  #pragma unroll
  for (int m = 0; m < 4; m++)
    #pragma unroll
    for (int n = 0; n < 4; n++)
      #pragma unroll
      for (int r = 0; r < 4; r++){
        const int row = m0 + wr + m*16 + (l >> 4)*4 + r;
        const int col = n0 + wc + n*16 + lrow;
        const float v = acc[m][n][r];
        if constexpr (sizeof(OutT) == 2) C[(size_t)row * N + col] = (OutT)f2bf(v);
        else                             C[(size_t)row * N + col] = v;
      }
}

// ---------------- 4. RoPE on Q and K, in place ----------------
// Q additionally scaled by log2(e)/sqrt(HD) so attention can use exp2 directly.
__global__ void k_rope(u16* __restrict__ Q, u16* __restrict__ Kp){
  const int idx = blockIdx.x * 256 + threadIdx.x;  // 4096*32*4 threads
  const int quad = idx & 3;
  const int h = (idx >> 2) & 31;
  const int row = idx >> 7;
  const int s = row & (SS - 1);
  const int i0 = quad * 8;
  u16* q = Q  + (size_t)row * H + h * HD;
  u16* k = Kp + (size_t)row * H + h * HD;
  uint4 q1v = *(const uint4*)(q + i0);
  uint4 q2v = *(const uint4*)(q + i0 + 32);
  uint4 k1v = *(const uint4*)(k + i0);
  uint4 k2v = *(const uint4*)(k + i0 + 32);
  u16* q1 = (u16*)&q1v; u16* q2 = (u16*)&q2v;
  u16* k1 = (u16*)&k1v; u16* k2 = (u16*)&k2v;
  const float sf = (float)s;
  const float QSC = 0.18033688011112042f;  // (1/8) * log2(e)
  #pragma unroll
  for (int e = 0; e < 8; e++){
    const int i = i0 + e;
    const float inv = exp2f(-0.4152410118609203f * (float)i);  // 10000^(-i/32)
    float rev = sf * inv * 0.15915494309189535f;               // radians -> revolutions
    rev -= floorf(rev);
    const float sn = __builtin_amdgcn_sinf(rev);
    const float cs = __builtin_amdgcn_cosf(rev);
    const float qa = bf2f(q1[e]), qb = bf2f(q2[e]);
    q1[e] = f2bf((qa*cs - qb*sn) * QSC);
    q2[e] = f2bf((qb*cs + qa*sn) * QSC);
    const float ka = bf2f(k1[e]), kb = bf2f(k2[e]);
    k1[e] = f2bf(ka*cs - kb*sn);
    k2[e] = f2bf(kb*cs + ka*sn);
  }
  *(uint4*)(q + i0)      = q1v;
  *(uint4*)(q + i0 + 32) = q2v;
  *(uint4*)(k + i0)      = k1v;
  *(uint4*)(k + i0 + 32) = k2v;
}

// ---------------- 5. causal flash attention (swapped QK^T, 32x32 mfma) ----------------
// block = 256 thr (4 waves x 32 q-rows = 128 q/block). Block x handles q-tiles
// {15-x, x} -> uniform 36 KV-iterations. Counted-vmcnt pipeline (T4): stage
// tile t+2 each iter; s_waitcnt vmcnt(4) + raw s_barrier (NO vmcnt(0) drain).
// K: 3 LDS buffers via global_load_lds; V: 2-deep reg prefetch -> transposed LDS.
__global__ __launch_bounds__(256, 2) void k_attn(
    const u16* __restrict__ Q, const u16* __restrict__ K,
    const u16* __restrict__ V, u16* __restrict__ O){
  __shared__ __align__(16) u16 Ks[3][64][64];   // swizzled: col ^ (row&7)*8
  __shared__ __align__(16) u16 Vs[2][64][72];   // transposed Vs[d][j], j ^ (d>>3)*8
  const int t = threadIdx.x, w = t >> 6, l = t & 63;
  const int x = blockIdx.x, bh = blockIdx.y;
  const int b = bh >> 5, h = bh & 31;
  const u16* kp = K + (size_t)(b*SS) * H + h * HD;
  const u16* vp = V + (size_t)(b*SS) * H + h * HD;
  const int sr = t >> 3, sc = (t & 7) * 8;      // staging: linear-LDS pattern
  const int ssc = sc ^ ((sr & 7) * 8);          // pre-swizzled global col for K
  const int hi = l >> 5, lq = l & 31;

  auto stageK = [&](int tile, int buf){
    const int jb = tile * 64;
    gload16(kp + (size_t)(jb + sr) * H + ssc,      &Ks[buf][sr][sc]);
    gload16(kp + (size_t)(jb + 32 + sr) * H + ssc, &Ks[buf][32 + sr][sc]);
  };
  auto loadV = [&](int tile, uint4* vv){
    const int jb = tile * 64;
    vv[0] = *(const uint4*)(vp + (size_t)(jb + sr) * H + sc);
    vv[1] = *(const uint4*)(vp + (size_t)(jb + 32 + sr) * H + sc);
  };
  auto publishV = [&](const uint4* vv, int buf){
    #pragma unroll
    for (int c = 0; c < 2; c++){
      const int j = c*32 + sr;
      const u16* pv = (const u16*)&vv[c];
      #pragma unroll
      for (int e = 0; e < 8; e++){
        const int d = sc + e;
        Vs[buf][d][j ^ ((d >> 3) * 8)] = pv[e];
      }
    }
  };

  #pragma unroll 1
  for (int pp = 0; pp < 2; pp++){
    const int qt = pp ? x : (15 - x);           // heavy pass first
    const int NT = 2*qt + 2;                    // even
    const int qw0 = qt*128 + w*32;
    const int qrow = qw0 + lq;                  // this lane's q index

    // Q fragments (B-operand of swapped QK^T): lane holds Q[qrow][c*16 + hi*8 + e]
    const u16* qptr = Q + (size_t)(b*SS + qrow) * H + h * HD + hi*8;
    bf16x8 qf[4];
    #pragma unroll
    for (int c = 0; c < 4; c++) qf[c] = *(const bf16x8*)(qptr + c*16);

    float mrun = -1e30f, lrun = 0.f;
    f32x16 oacc[2] = {};
    uint4 vvE[2], vvO[2];

    // ---- prologue: stage tiles 0 (->vvE) and 1 (->vvO) ----
    stageK(0, 0); loadV(0, vvE);
    stageK(1, 1); loadV(1, vvO);
    asm volatile("s_waitcnt vmcnt(4)" ::: "memory");   // stage(0) complete
    publishV(vvE, 0);
    asm volatile("s_waitcnt lgkmcnt(0)" ::: "memory");
    __builtin_amdgcn_s_barrier();

    // one pipelined body; p = jt&1 (compile-time at call site)
    auto body = [&](int jt, int p, uint4* vvSelf, const uint4* vvOther){
      const int j0 = jt * 64;
      if (jt + 2 < NT){ stageK(jt + 2, (jt + 2) % 3); loadV(jt + 2, vvSelf); }

      if (j0 <= qw0){   // wave has live rows in this tile
        const int kbuf = jt % 3;
        // ---- S^T = K . Q^T ----
        f32x16 sv[2] = {};
        __builtin_amdgcn_s_setprio(1);
        #pragma unroll
        for (int kb = 0; kb < 2; kb++){
          const int row = kb*32 + lq;
          #pragma unroll
          for (int c = 0; c < 4; c++){
            bf16x8 kf = *(const bf16x8*)&Ks[kbuf][row][(c*16 + hi*8) ^ ((row & 7) * 8)];
            sv[kb] = __builtin_amdgcn_mfma_f32_32x32x16_bf16(kf, qf[c], sv[kb], 0, 0, 0);
          }
        }
        __builtin_amdgcn_s_setprio(0);
        // ---- causal mask (diagonal-touching tiles only) ----
        if (j0 + 63 > qw0){
          #pragma unroll
          for (int kb = 0; kb < 2; kb++)
            #pragma unroll
            for (int r = 0; r < 16; r++){
              const int kg = j0 + kb*32 + (r & 3) + 8*(r >> 2) + 4*hi;
              if (kg > qrow) sv[kb][r] = -1e30f;
            }
        }
        // ---- online softmax (exp2 domain), tree reduce, partner lane l^32 ----
        float t16[16], t8[8], t4[4];
        #pragma unroll
        for (int r = 0; r < 16; r++) t16[r] = fmaxf(sv[0][r], sv[1][r]);
        #pragma unroll
        for (int r = 0; r < 8; r++) t8[r] = fmaxf(t16[r], t16[r+8]);
        #pragma unroll
        for (int r = 0; r < 4; r++) t4[r] = fmaxf(t8[r], t8[r+4]);
        float tm = fmaxf(fmaxf(t4[0], t4[2]), fmaxf(t4[1], t4[3]));
        tm = fmaxf(tm, __shfl_xor(tm, 32, 64));
        if (__any(tm > mrun)){       // exact: skipped iff fac == 1.0 for all lanes
          const float mn = fmaxf(mrun, tm);
          const float fac = exp2f(mrun - mn);
          mrun = mn;
          lrun *= fac;
          #pragma unroll
          for (int db = 0; db < 2; db++)
            #pragma unroll
            for (int r = 0; r < 16; r++) oacc[db][r] *= fac;
        }
        #pragma unroll
        for (int kb = 0; kb < 2; kb++)
          #pragma unroll
          for (int r = 0; r < 16; r++) sv[kb][r] = exp2f(sv[kb][r] - mrun);
        float s16[16], s8[8], s4[4];
        #pragma unroll
        for (int r = 0; r < 16; r++) s16[r] = sv[0][r] + sv[1][r];
        #pragma unroll
        for (int r = 0; r < 8; r++) s8[r] = s16[r] + s16[r+8];
        #pragma unroll
        for (int r = 0; r < 4; r++) s4[r] = s8[r] + s8[r+4];
        float rs = (s4[0] + s4[1]) + (s4[2] + s4[3]);
        rs += __shfl_xor(rs, 32, 64);
        lrun += rs;
        // ---- build PV B-frags: cvt_pk pairs, exchange halves via xor-32 ----
        u32x4 pw[4];
        #pragma unroll
        for (int kb = 0; kb < 2; kb++){
          #pragma unroll
          for (int half = 0; half < 2; half++){
            const int rb = half * 8;
            const u32 own0 = pk2(sv[kb][rb+0], sv[kb][rb+1]);
            const u32 own1 = pk2(sv[kb][rb+2], sv[kb][rb+3]);
            const u32 own2 = pk2(sv[kb][rb+4], sv[kb][rb+5]);
            const u32 own3 = pk2(sv[kb][rb+6], sv[kb][rb+7]);
            const u32 s0 = hi ? own0 : own2;
            const u32 s1 = hi ? own1 : own3;
            const u32 r0 = __shfl_xor(s0, 32, 64);
            const u32 r1 = __shfl_xor(s1, 32, 64);
            u32x4 pv;
            pv[0] = hi ? r0 : own0;
            pv[1] = hi ? r1 : own1;
            pv[2] = hi ? own2 : r0;
            pv[3] = hi ? own3 : r1;
            pw[kb*2 + half] = pv;
          }
        }
        // ---- O^T += V^T . P^T ----
        __builtin_amdgcn_s_setprio(1);
        #pragma unroll
        for (int db = 0; db < 2; db++){
          const int d = db*32 + lq;
          #pragma unroll
          for (int tt = 0; tt < 4; tt++){
            bf16x8 vf = *(const bf16x8*)&Vs[p][d][(tt*16 + hi*8) ^ ((d >> 3) * 8)];
            bf16x8 pfr = __builtin_bit_cast(bf16x8, pw[tt]);
            oacc[db] = __builtin_amdgcn_mfma_f32_32x32x16_bf16(vf, pfr, oacc[db], 0, 0, 0);
          }
        }
        __builtin_amdgcn_s_setprio(0);
      }

      // counted wait: stage(jt+1) [K in LDS + V regs] complete; stage(jt+2) stays in flight
      if (jt + 2 < NT) asm volatile("s_waitcnt vmcnt(4)" ::: "memory");
      else             asm volatile("s_waitcnt vmcnt(0)" ::: "memory");
      if (jt + 1 < NT) publishV(vvOther, p ^ 1);
      asm volatile("s_waitcnt lgkmcnt(0)" ::: "memory");
      __builtin_amdgcn_s_barrier();
    };

    #pragma unroll 1
    for (int jt2 = 0; jt2 < NT; jt2 += 2){
      body(jt2,     0, vvE, vvO);
      body(jt2 + 1, 1, vvO, vvE);
    }

    // ---- epilogue: lane owns q-row qrow; d = (r&3)+8*(r>>2)+4*hi + 32*db ----
    const float rl = 1.0f / lrun;
    u16* op = O + (size_t)(b*SS + qrow) * H + h * HD;
    #pragma unroll
    for (int db = 0; db < 2; db++)
      #pragma unroll
      for (int rq = 0; rq < 4; rq++){
        ushort4 o4;
        o4.x = f2bf(oacc[db][rq*4 + 0] * rl);
        o4.y = f2bf(oacc[db][rq*4 + 1] * rl);
        o4.z = f2bf(oacc[db][rq*4 + 2] * rl);
        o4.w = f2bf(oacc[db][rq*4 + 3] * rl);
        *(ushort4*)(op + db*32 + rq*8 + 4*hi) = o4;
      }
  }
}

extern "C" void kernel_launch(void* const* d_in, const int* in_sizes, int n_in,
                              void* d_out, int out_size, void* d_ws, size_t ws_size,
                              hipStream_t stream){
  (void)in_sizes; (void)n_in; (void)out_size; (void)ws_size;
  const float* hs = (const float*)d_in[0];
  // d_in[1] = attention_mask (causal, implemented analytically)
  const float* wq = (const float*)d_in[2];
  const float* wk = (const float*)d_in[3];
  const float* wv = (const float*)d_in[4];
  const float* wo = (const float*)d_in[5];
  float* out = (float*)d_out;
  char* ws = (char*)d_ws;

  // workspace layout (bytes): Xb 16.8M | Wqt/Wkt/Wvt (contiguous, = flattened
  // Bt[6144][2048]) + Wot 4x8.4M | Vb 16.8M | Ob 16.8M  (~84MB)
  u16* Xb  = (u16*)ws;
  u16* Wqt = (u16*)(ws + (size_t)MM * H * 2);
  u16* Wkt = Wqt + (size_t)H * H;
  u16* Wvt = Wkt + (size_t)H * H;
  u16* Wot = Wvt + (size_t)H * H;
  u16* Vb  = Wot + (size_t)H * H;
  u16* Ob  = Vb  + (size_t)MM * H;
  // Q,K (bf16) live in d_out's 33.5MB until the final GEMM overwrites it
  u16* Qb  = (u16*)d_out;
  u16* Kb  = Qb + (size_t)MM * H;

  k_cvt<<<8192, 256, 0, stream>>>(hs, Xb);
  k_wtrans<<<dim3(64, 64, 4), dim3(32, 8), 0, stream>>>(wq, wk, wv, wo, Wqt, Wkt, Wvt, Wot);
  k_gemm8<<<512, 512, 0, stream>>>(Xb, Wqt, Qb, Kb, Vb, MM, H);
  k_rope<<<2048, 256, 0, stream>>>(Qb, Kb);
  k_attn<<<dim3(8, 64), 256, 0, stream>>>(Qb, Kb, Vb, Ob);
  k_gemm<float><<<dim3(32, 16, 1), 256, 0, stream>>>(Ob, Wot, Wot, Wot, out, out, out, MM, H, H);
}